// Round 5
// baseline (33.279 us; speedup 1.0000x reference)
//
#include <hip/hip_runtime.h>

#define NPART 128
#define NDIM  128
#define BATCH 4096
#define SPB   2                       // samples per block (mix)
#define NBLK  (BATCH / SPB)           // 2048
#define NXCD  8
#define NB    16                      // prep blocks
#define SLICE (BATCH / NB)            // 256 samples per prep block

// ---------------------------------------------------------------------------
// Phase 1: per-block histogram of randind. 16 blocks x 256 threads.
// h[B][128] -> ws
// ---------------------------------------------------------------------------
__global__ __launch_bounds__(256)
void hist_kernel(const int* __restrict__ randind, int* __restrict__ h) {
    __shared__ int hist[NPART];
    const int t = threadIdx.x, B = blockIdx.x;
    if (t < NPART) hist[t] = 0;
    __syncthreads();
    atomicAdd(&hist[randind[B * SLICE + t]], 1);
    __syncthreads();
    if (t < NPART) h[B * NPART + t] = hist[t];
}

// ---------------------------------------------------------------------------
// Phase 2: scatter. 16 blocks x 256 threads. Each block loads the full
// [16][128] histogram matrix, locally computes the global exclusive offsets
// (cheap redundant 128-wide scan), then scatters its 256-sample slice into
// list (packed (sid<<7)|ind). Also fuses softmax -> wout and indout writes.
// ---------------------------------------------------------------------------
__global__ __launch_bounds__(256)
void scatter_kernel(const float* __restrict__ logp,
                    const int*   __restrict__ randind,
                    const int*   __restrict__ h,
                    int*   __restrict__ list,
                    float* __restrict__ wout,
                    float* __restrict__ indout) {
    __shared__ int   hh[NB * NPART];
    __shared__ int   tot[NPART], sc[NPART], cursor[NPART];
    __shared__ float p[NPART];
    const int t = threadIdx.x, B = blockIdx.x;

    for (int k = t; k < NB * NPART; k += 256) hh[k] = h[k];

    if (t < 64) {                      // softmax over 128 by wave 0
        float a = logp[t], b = logp[t + 64];
        float m = fmaxf(a, b);
        #pragma unroll
        for (int o = 32; o > 0; o >>= 1) m = fmaxf(m, __shfl_xor(m, o));
        float ea = expf(a - m), eb = expf(b - m);
        float s = ea + eb;
        #pragma unroll
        for (int o = 32; o > 0; o >>= 1) s += __shfl_xor(s, o);
        float inv = 1.0f / s;
        p[t] = ea * inv;  p[t + 64] = eb * inv;
    }
    __syncthreads();

    if (t < NPART) {
        int total = 0, partial = 0;
        #pragma unroll
        for (int b = 0; b < NB; ++b) {
            int v = hh[b * NPART + t];
            total += v;
            if (b < B) partial += v;
        }
        tot[t] = total;
        sc[t]  = total;
        cursor[t] = partial;           // temp: intra-slice base
    }
    __syncthreads();
    #pragma unroll
    for (int d = 1; d < NPART; d <<= 1) {   // Hillis-Steele inclusive scan
        int v = 0;
        if (t < NPART && t >= d) v = sc[t - d];
        __syncthreads();
        if (t < NPART) sc[t] += v;
        __syncthreads();
    }
    if (t < NPART) cursor[t] += sc[t] - tot[t];  // global exclusive + partial
    __syncthreads();

    const int s   = B * SLICE + t;
    const int ind = randind[s];
    const int pos = atomicAdd(&cursor[ind], 1);
    list[pos] = (s << 7) | ind;
    wout[s]   = p[ind];
    indout[s] = (float)ind;            // exact for 0..127
}

// ---------------------------------------------------------------------------
// Compute: 2048 blocks x 128 threads, 2 sorted samples per block.
// y read via wave-uniform global float4 loads (L1-hot) -- no LDS, no barrier.
// Sigma staged 16-deep for MLP. XCD-chunked swizzle for L2 residency.
// ---------------------------------------------------------------------------
__global__ __launch_bounds__(NDIM)
void mix_kernel(const float* __restrict__ gaussian,  // [BATCH, NDIM]
                const float* __restrict__ pos,       // [NPART, NDIM]
                const float* __restrict__ sigma,     // [NPART, NDIM, NDIM]
                const int*   __restrict__ list,      // [BATCH] packed, sorted
                float* __restrict__ out) {           // [BATCH, NDIM]
    const int g   = blockIdx.x;
    const int cpx = NBLK / NXCD;
    const int sg  = (g % NXCD) * cpx + g / NXCD;    // bijective (2048 % 8 == 0)
    const int p0  = sg * SPB;
    const int i   = threadIdx.x;

    const int e0 = list[p0], e1 = list[p0 + 1];     // uniform -> scalarized
    const int sid0 = e0 >> 7, ind0 = e0 & 127;
    const int sid1 = e1 >> 7, ind1 = e1 & 127;

    const float* y0 = gaussian + sid0 * NDIM;
    const float* y1 = gaussian + sid1 * NDIM;

    float acc0 = 0.f, acc1 = 0.f;

    if (ind0 == ind1) {   // same particle (common case): share sigma row
        const float4* row = reinterpret_cast<const float4*>(
            sigma + ((size_t)ind0 * NDIM + i) * NDIM);
        #pragma unroll
        for (int r = 0; r < 2; ++r) {
            float4 sv[16];
            #pragma unroll
            for (int u = 0; u < 16; ++u) sv[u] = row[r * 16 + u];
            #pragma unroll
            for (int u = 0; u < 16; ++u) {
                float4 a = *reinterpret_cast<const float4*>(y0 + r * 64 + u * 4);
                float4 b = *reinterpret_cast<const float4*>(y1 + r * 64 + u * 4);
                acc0 += sv[u].x * a.x + sv[u].y * a.y + sv[u].z * a.z + sv[u].w * a.w;
                acc1 += sv[u].x * b.x + sv[u].y * b.y + sv[u].z * b.z + sv[u].w * b.w;
            }
        }
    } else {              // bucket boundary: two rows, 8-deep staging
        const float4* row0 = reinterpret_cast<const float4*>(
            sigma + ((size_t)ind0 * NDIM + i) * NDIM);
        const float4* row1 = reinterpret_cast<const float4*>(
            sigma + ((size_t)ind1 * NDIM + i) * NDIM);
        #pragma unroll
        for (int r = 0; r < 4; ++r) {
            float4 sv0[8], sv1[8];
            #pragma unroll
            for (int u = 0; u < 8; ++u) { sv0[u] = row0[r * 8 + u]; sv1[u] = row1[r * 8 + u]; }
            #pragma unroll
            for (int u = 0; u < 8; ++u) {
                float4 a = *reinterpret_cast<const float4*>(y0 + r * 32 + u * 4);
                float4 b = *reinterpret_cast<const float4*>(y1 + r * 32 + u * 4);
                acc0 += sv0[u].x * a.x + sv0[u].y * a.y + sv0[u].z * a.z + sv0[u].w * a.w;
                acc1 += sv1[u].x * b.x + sv1[u].y * b.y + sv1[u].z * b.z + sv1[u].w * b.w;
            }
        }
    }

    out[sid0 * NDIM + i] = pos[ind0 * NDIM + i] + acc0;
    out[sid1 * NDIM + i] = pos[ind1 * NDIM + i] + acc1;
}

extern "C" void kernel_launch(void* const* d_in, const int* in_sizes, int n_in,
                              void* d_out, int out_size, void* d_ws, size_t ws_size,
                              hipStream_t stream) {
    const float* gaussian = (const float*)d_in[0];   // [4096,128]
    const float* logp     = (const float*)d_in[1];   // [128,1]
    const float* pos      = (const float*)d_in[2];   // [128,128]
    const float* sigma    = (const float*)d_in[3];   // [128,128,128]
    const int*   randind  = (const int*)d_in[4];     // [4096]

    float* out    = (float*)d_out;            // [4096*128]
    float* wout   = out + BATCH * NDIM;       // [4096]
    float* indout = wout + BATCH;             // [4096]

    int* h    = (int*)d_ws;                   // [16*128] per-block histograms
    int* list = h + NB * NPART;               // [4096] packed (sid<<7)|ind

    hist_kernel<<<NB, 256, 0, stream>>>(randind, h);
    scatter_kernel<<<NB, 256, 0, stream>>>(logp, randind, h, list, wout, indout);
    mix_kernel<<<NBLK, NDIM, 0, stream>>>(gaussian, pos, sigma, list, out);
}

// Round 8
// 25.107 us; speedup vs baseline: 1.3255x; 1.3255x over previous
//
#include <hip/hip_runtime.h>

#define NPART 128
#define NDIM  128
#define BATCH 4096
#define NB    16                      // prep blocks
#define SLICE (BATCH / NB)            // 256 samples per prep block
#define BPP   4                       // mix blocks per particle
#define NBLK2 (NPART * BPP)           // 512 mix blocks
#define NXCD  8

// ---------------------------------------------------------------------------
// Phase 1: per-block histogram of randind. 16 blocks x 256 threads.
// ---------------------------------------------------------------------------
__global__ __launch_bounds__(256)
void hist_kernel(const int* __restrict__ randind, int* __restrict__ h) {
    __shared__ int hist[NPART];
    const int t = threadIdx.x, B = blockIdx.x;
    if (t < NPART) hist[t] = 0;
    __syncthreads();
    atomicAdd(&hist[randind[B * SLICE + t]], 1);
    __syncthreads();
    if (t < NPART) h[B * NPART + t] = hist[t];
}

// ---------------------------------------------------------------------------
// Phase 2: scatter. 16 blocks x 256 threads. Redundant 128-wide scan of the
// [16][128] histogram matrix, scatter slice into list (packed (sid<<7)|ind).
// Fuses softmax -> wout, indout. Block 0 also writes offs[129] for mix.
// ---------------------------------------------------------------------------
__global__ __launch_bounds__(256)
void scatter_kernel(const float* __restrict__ logp,
                    const int*   __restrict__ randind,
                    const int*   __restrict__ h,
                    int*   __restrict__ list,
                    int*   __restrict__ offs,      // ws: [129]
                    float* __restrict__ wout,
                    float* __restrict__ indout) {
    __shared__ int   hh[NB * NPART];
    __shared__ int   tot[NPART], sc[NPART], cursor[NPART];
    __shared__ float p[NPART];
    const int t = threadIdx.x, B = blockIdx.x;

    for (int k = t; k < NB * NPART; k += 256) hh[k] = h[k];

    if (t < 64) {                      // softmax over 128 by wave 0
        float a = logp[t], b = logp[t + 64];
        float m = fmaxf(a, b);
        #pragma unroll
        for (int o = 32; o > 0; o >>= 1) m = fmaxf(m, __shfl_xor(m, o));
        float ea = expf(a - m), eb = expf(b - m);
        float s = ea + eb;
        #pragma unroll
        for (int o = 32; o > 0; o >>= 1) s += __shfl_xor(s, o);
        float inv = 1.0f / s;
        p[t] = ea * inv;  p[t + 64] = eb * inv;
    }
    __syncthreads();

    if (t < NPART) {
        int total = 0, partial = 0;
        #pragma unroll
        for (int b = 0; b < NB; ++b) {
            int v = hh[b * NPART + t];
            total += v;
            if (b < B) partial += v;
        }
        tot[t] = total;
        sc[t]  = total;
        cursor[t] = partial;
    }
    __syncthreads();
    #pragma unroll
    for (int d = 1; d < NPART; d <<= 1) {   // Hillis-Steele inclusive scan
        int v = 0;
        if (t < NPART && t >= d) v = sc[t - d];
        __syncthreads();
        if (t < NPART) sc[t] += v;
        __syncthreads();
    }
    if (t < NPART) {
        int excl = sc[t] - tot[t];
        cursor[t] += excl;
        if (B == 0) offs[t] = excl;
    }
    if (B == 0 && t == 0) offs[NPART] = BATCH;
    __syncthreads();

    const int s   = B * SLICE + t;
    const int ind = randind[s];
    const int pos = atomicAdd(&cursor[ind], 1);
    list[pos] = (s << 7) | ind;
    wout[s]   = p[ind];
    indout[s] = (float)ind;            // exact for 0..127
}

// ---------------------------------------------------------------------------
// Compute: 512 blocks x 128 threads; block = quarter of one particle bucket.
// sigma_p staged coalesced->LDS once, row -> registers (XOR-swizzled b128
// reads), then per-sample: scalar (SGPR) y loads + 128 VGPR fmacs.
// ---------------------------------------------------------------------------
__global__ __launch_bounds__(128)
void mix_kernel(const float* __restrict__ gaussian,  // [BATCH, NDIM]
                const float* __restrict__ pos,       // [NPART, NDIM]
                const float* __restrict__ sigma,     // [NPART, NDIM, NDIM]
                const int*   __restrict__ list,      // [BATCH] packed, sorted
                const int*   __restrict__ offs,      // [129]
                float* __restrict__ out) {           // [BATCH, NDIM]
    const int g  = blockIdx.x;
    // XCD-chunked bijective swizzle (512 % 8 == 0): a particle's 4 sibling
    // blocks land on the same XCD -> sigma_p HBM-fetched once, L2-served 3x.
    const int sg = (g % NXCD) * (NBLK2 / NXCD) + g / NXCD;
    const int p  = sg >> 2;            // particle
    const int q  = sg & 3;             // quarter of bucket
    const int i  = threadIdx.x;        // output row

    const int b0 = offs[p], b1 = offs[p + 1];
    const int n  = b1 - b0;
    const int s0 = b0 + (n * q) / BPP;
    const int s1 = b0 + (n * (q + 1)) / BPP;
    if (s0 == s1) return;              // uniform across block

    // --- stage sigma_p coalesced into LDS (XOR-swizzled 16B units) ---
    __shared__ float4 smat[NDIM * 32];           // 64 KB
    const float4* src = reinterpret_cast<const float4*>(
        sigma + (size_t)p * NDIM * NDIM);
    #pragma unroll
    for (int w = 0; w < 32; ++w) {
        int idx = w * NDIM + i;                  // linear float4 index
        int r = idx >> 5, u = idx & 31;
        smat[r * 32 + (u ^ (r & 7))] = src[idx];
    }
    __syncthreads();

    // --- row i -> 32 float4 registers (8-way-spread b128 reads) ---
    float4 sr[32];
    #pragma unroll
    for (int u = 0; u < 32; ++u)
        sr[u] = smat[i * 32 + (u ^ (i & 7))];

    const float posv = pos[p * NDIM + i];

    // --- per-sample: uniform y row (scalar loads) + register fmacs ---
    for (int s = s0; s < s1; ++s) {
        const int e   = __builtin_amdgcn_readfirstlane(list[s]);
        const int sid = e >> 7;
        const float4* y = reinterpret_cast<const float4*>(
            gaussian + (size_t)sid * NDIM);
        float a0 = 0.f, a1 = 0.f, a2 = 0.f, a3 = 0.f;
        #pragma unroll
        for (int u = 0; u < 32; ++u) {
            float4 yv = y[u];                    // wave-uniform -> s_load
            float4 sv = sr[u];
            a0 += sv.x * yv.x;  a1 += sv.y * yv.y;
            a2 += sv.z * yv.z;  a3 += sv.w * yv.w;
        }
        out[sid * NDIM + i] = posv + ((a0 + a1) + (a2 + a3));
    }
}

extern "C" void kernel_launch(void* const* d_in, const int* in_sizes, int n_in,
                              void* d_out, int out_size, void* d_ws, size_t ws_size,
                              hipStream_t stream) {
    const float* gaussian = (const float*)d_in[0];   // [4096,128]
    const float* logp     = (const float*)d_in[1];   // [128,1]
    const float* pos      = (const float*)d_in[2];   // [128,128]
    const float* sigma    = (const float*)d_in[3];   // [128,128,128]
    const int*   randind  = (const int*)d_in[4];     // [4096]

    float* out    = (float*)d_out;            // [4096*128]
    float* wout   = out + BATCH * NDIM;       // [4096]
    float* indout = wout + BATCH;             // [4096]

    int* h    = (int*)d_ws;                   // [16*128]
    int* offs = h + NB * NPART;               // [129]
    int* list = offs + (NPART + 1);           // [4096]

    hist_kernel<<<NB, 256, 0, stream>>>(randind, h);
    scatter_kernel<<<NB, 256, 0, stream>>>(logp, randind, h, list, offs, wout, indout);
    mix_kernel<<<NBLK2, NDIM, 0, stream>>>(gaussian, pos, sigma, list, offs, out);
}

// Round 9
// 20.376 us; speedup vs baseline: 1.6332x; 1.2322x over previous
//
#include <hip/hip_runtime.h>

#define NPART 128
#define NDIM  128
#define BATCH 4096
#define BPP   4                       // mix blocks per particle
#define NBLK2 (NPART * BPP)           // 512 mix blocks
#define NXCD  8

// ---------------------------------------------------------------------------
// Prep: ONE block x 1024 threads. softmax(logp)->p_ws; LDS-atomic histogram
// of randind; 128-wide scan -> offs; scatter sample ids into sorted list.
// (Bucket-internal order is timing-dependent, but all consumer writes are
// keyed by sid and particle only -> output deterministic.)
// ---------------------------------------------------------------------------
__global__ __launch_bounds__(1024)
void prep_kernel(const float* __restrict__ logp,
                 const int*   __restrict__ randind,
                 int*   __restrict__ list,      // ws: [4096] (sid<<7)|ind
                 int*   __restrict__ offs,      // ws: [129]
                 float* __restrict__ p_ws) {    // ws: [128] softmax probs
    __shared__ int cnt[NPART], sc[NPART], cursor[NPART];
    const int t = threadIdx.x;

    if (t < 64) {                      // softmax over 128 by wave 0
        float a = logp[t], b = logp[t + 64];
        float m = fmaxf(a, b);
        #pragma unroll
        for (int o = 32; o > 0; o >>= 1) m = fmaxf(m, __shfl_xor(m, o));
        float ea = expf(a - m), eb = expf(b - m);
        float s = ea + eb;
        #pragma unroll
        for (int o = 32; o > 0; o >>= 1) s += __shfl_xor(s, o);
        float inv = 1.0f / s;
        p_ws[t] = ea * inv;  p_ws[t + 64] = eb * inv;
    }
    if (t < NPART) cnt[t] = 0;
    __syncthreads();

    #pragma unroll
    for (int k = 0; k < BATCH / 1024; ++k)
        atomicAdd(&cnt[randind[t + k * 1024]], 1);
    __syncthreads();

    if (t < NPART) sc[t] = cnt[t];
    __syncthreads();
    #pragma unroll
    for (int d = 1; d < NPART; d <<= 1) {   // Hillis-Steele inclusive scan
        int v = 0;
        if (t < NPART && t >= d) v = sc[t - d];
        __syncthreads();
        if (t < NPART) sc[t] += v;
        __syncthreads();
    }
    if (t < NPART) {
        int excl = sc[t] - cnt[t];
        cursor[t] = excl;
        offs[t]   = excl;
    }
    if (t == 0) offs[NPART] = BATCH;
    __syncthreads();

    #pragma unroll
    for (int k = 0; k < BATCH / 1024; ++k) {
        const int s   = t + k * 1024;
        const int ind = randind[s];
        const int pos = atomicAdd(&cursor[ind], 1);
        list[pos] = (s << 7) | ind;
    }
}

// ---------------------------------------------------------------------------
// Compute: 512 blocks x 256 threads; block = quarter of one particle bucket,
// two 128-lane halves process alternating samples. sigma_p staged coalesced
// ->LDS (XOR-swizzled), row -> 32 float4 registers, per-sample scalar y loads
// + register fmacs. Also emits wout/indout (one lane per sample).
// ---------------------------------------------------------------------------
__global__ __launch_bounds__(256)
void mix_kernel(const float* __restrict__ gaussian,  // [BATCH, NDIM]
                const float* __restrict__ pos,       // [NPART, NDIM]
                const float* __restrict__ sigma,     // [NPART, NDIM, NDIM]
                const int*   __restrict__ list,      // [BATCH] packed, sorted
                const int*   __restrict__ offs,      // [129]
                const float* __restrict__ p_ws,      // [128]
                float* __restrict__ out,             // [BATCH, NDIM]
                float* __restrict__ wout,            // [BATCH]
                float* __restrict__ indout) {        // [BATCH]
    const int g  = blockIdx.x;
    // XCD-chunked bijective swizzle (512 % 8 == 0): a particle's 4 sibling
    // blocks land on the same XCD -> sigma_p HBM-fetched once, L2-served 3x.
    const int sg = (g % NXCD) * (NBLK2 / NXCD) + g / NXCD;
    const int p  = sg >> 2;            // particle
    const int q  = sg & 3;             // quarter of bucket
    const int t  = threadIdx.x;
    const int i  = t & 127;            // output row
    const int hf = t >> 7;             // sample-parity half

    const int b0 = offs[p], b1 = offs[p + 1];
    const int n  = b1 - b0;
    const int s0 = b0 + (n * q) / BPP;
    const int s1 = b0 + (n * (q + 1)) / BPP;
    if (s0 >= s1) return;              // block-uniform, before barrier

    // --- stage sigma_p coalesced into LDS (XOR-swizzled 16B units) ---
    __shared__ float4 smat[NDIM * 32];           // 64 KB
    const float4* src = reinterpret_cast<const float4*>(
        sigma + (size_t)p * NDIM * NDIM);
    #pragma unroll
    for (int w = 0; w < 16; ++w) {
        int idx = w * 256 + t;                   // linear float4 index
        int r = idx >> 5, u = idx & 31;
        smat[r * 32 + (u ^ (r & 7))] = src[idx];
    }
    __syncthreads();

    // --- row i -> 32 float4 registers (8-way-spread b128 reads) ---
    float4 sr[32];
    #pragma unroll
    for (int u = 0; u < 32; ++u)
        sr[u] = smat[i * 32 + (u ^ (i & 7))];

    const float posv = pos[p * NDIM + i];
    const float pw   = p_ws[p];

    // --- per-sample: uniform y row (scalar loads) + register fmacs ---
    for (int s = s0 + hf; s < s1; s += 2) {
        const int e   = __builtin_amdgcn_readfirstlane(list[s]);
        const int sid = e >> 7;
        const float4* y = reinterpret_cast<const float4*>(
            gaussian + (size_t)sid * NDIM);
        float a0 = 0.f, a1 = 0.f, a2 = 0.f, a3 = 0.f;
        #pragma unroll
        for (int u = 0; u < 32; ++u) {
            float4 yv = y[u];                    // wave-uniform -> s_load
            float4 sv = sr[u];
            a0 += sv.x * yv.x;  a1 += sv.y * yv.y;
            a2 += sv.z * yv.z;  a3 += sv.w * yv.w;
        }
        out[sid * NDIM + i] = posv + ((a0 + a1) + (a2 + a3));
        if (i == 0) {
            wout[sid]   = pw;
            indout[sid] = (float)p;              // exact for 0..127
        }
    }
}

extern "C" void kernel_launch(void* const* d_in, const int* in_sizes, int n_in,
                              void* d_out, int out_size, void* d_ws, size_t ws_size,
                              hipStream_t stream) {
    const float* gaussian = (const float*)d_in[0];   // [4096,128]
    const float* logp     = (const float*)d_in[1];   // [128,1]
    const float* pos      = (const float*)d_in[2];   // [128,128]
    const float* sigma    = (const float*)d_in[3];   // [128,128,128]
    const int*   randind  = (const int*)d_in[4];     // [4096]

    float* out    = (float*)d_out;            // [4096*128]
    float* wout   = out + BATCH * NDIM;       // [4096]
    float* indout = wout + BATCH;             // [4096]

    int*   list = (int*)d_ws;                 // [4096]
    int*   offs = list + BATCH;               // [129]
    float* p_ws = (float*)(offs + NPART + 1); // [128]

    prep_kernel<<<1, 1024, 0, stream>>>(logp, randind, list, offs, p_ws);
    mix_kernel<<<NBLK2, 256, 0, stream>>>(gaussian, pos, sigma, list, offs,
                                          p_ws, out, wout, indout);
}